// Round 4
// baseline (149.705 us; speedup 1.0000x reference)
//
#include <hip/hip_runtime.h>
#include <stdint.h>

namespace {
constexpr int BATCH  = 512;
constexpr int CBS    = 320;       // combined batch size
constexpr int R      = 64;        // rank
constexpr int K      = 4096;
constexpr int NADAPT = 80;
constexpr int SPLIT  = 8;         // k-split across blocks (slice s -> XCD s)
constexpr int KS     = K / SPLIT; // 512 k per block
constexpr int TK     = 64;        // k-tile staged in LDS
constexpr int NT     = 256;       // 4 waves
constexpr int NW     = NT / 64;
constexpr int NTILES = KS / TK;   // 8
constexpr int G      = 4;         // combos grouped per block (share one adapter)
constexpr int MAXG   = (CBS + (G - 1) * NADAPT) / G;  // 140: max sum ceil(n_w/4)

// ws layout (int offsets): gcnt @0..140, gwid @256.., gc @512.. (140*4);
// x_bf16 at byte 8192.
constexpr size_t WS_XB_OFF = 8192;
constexpr size_t WS_NEEDED = WS_XB_OFF + (size_t)BATCH * K * 2;  // ~4.2 MiB

__device__ inline uint16_t f2bf(float f) {   // RNE fp32 -> bf16
    uint32_t u = __float_as_uint(f);
    u += 0x7fffu + ((u >> 16) & 1u);
    return (uint16_t)(u >> 16);
}
__device__ inline float bflo(uint32_t u) { return __uint_as_float(u << 16); }
__device__ inline float bfhi(uint32_t u) { return __uint_as_float(u & 0xffff0000u); }
}

// ---- pre-pass 1: build same-wid groups of up to G combos ----
__global__ void groups_build(const int* __restrict__ wids,
                             int* __restrict__ gcnt, int* __restrict__ gwid,
                             int* __restrict__ gc)
{
    __shared__ int hist[NADAPT];
    __shared__ int offs[NADAPT];
    __shared__ int gbase[NADAPT];
    const int t = threadIdx.x;           // 0..319
    if (t < NADAPT) { hist[t] = 0; offs[t] = 0; }
    if (t < MAXG) gcnt[t] = 0;           // ws is poisoned 0xAA: must zero
    __syncthreads();
    atomicAdd(&hist[wids[t]], 1);
    __syncthreads();
    if (t == 0) {
        int run = 0;
        for (int w = 0; w < NADAPT; ++w) { gbase[w] = run; run += (hist[w] + G - 1) / G; }
    }
    __syncthreads();
    const int w   = wids[t];
    const int rk  = atomicAdd(&offs[w], 1);
    const int gid = gbase[w] + (rk >> 2);
    gc[gid * G + (rk & 3)] = t;
    gwid[gid] = w;                       // benign same-value race
    atomicAdd(&gcnt[gid], 1);
}

// ---- pre-pass 2: x fp32 -> bf16 (halves traffic; per-XCD slice is L2-resident) ----
__global__ __launch_bounds__(256)
void cvt_x(const float* __restrict__ x, uint16_t* __restrict__ xb)
{
    const int i = blockIdx.x * 256 + threadIdx.x;   // over BATCH*K/4 float4s
    const float4 v = ((const float4*)x)[i];
    ushort4 o;
    o.x = f2bf(v.x); o.y = f2bf(v.y); o.z = f2bf(v.z); o.w = f2bf(v.w);
    ((ushort4*)xb)[i] = o;
}

// ---- main: block (gid, s): group of <=4 combos sharing adapter, k-slice s ----
__global__ __launch_bounds__(NT)
void lora_main(const int* __restrict__ xids,
               const float* __restrict__ A,
               const uint16_t* __restrict__ xb,
               const int* __restrict__ gcnt, const int* __restrict__ gwid,
               const int* __restrict__ gc,
               float* __restrict__ out)
{
    // xs: packed bf16 pairs, [g][p(=k/2, 32)][r(64)] u32, write-swizzled
    // r' = r ^ ((jq&1?..)<<4): staging writes 2-way bank (free), reads b128.
    __shared__ uint32_t xs[G * (TK / 2) * R];   // 32 KiB
    __shared__ float red[G * NW * R];           // 4 KiB

    const int bid = blockIdx.x;
    const int gid = bid >> 3;
    const int s   = bid & 7;
    const int cnt = gcnt[gid];
    if (cnt == 0) return;                       // padded/empty group
    const int wid = gwid[gid];
    const float* __restrict__ Aw = A + (size_t)wid * (K * R);

    const int t    = threadIdx.x;
    const int wave = t >> 6;
    const int lane = t & 63;
    const int r4   = lane & 15;
    const int kq   = lane >> 4;
    const int rw   = t >> 2;        // staging row 0..63
    const int jq   = t & 3;         // staging 16-k chunk
    const int rsw  = rw ^ (jq << 4);            // write swizzle (mod-32: 2-way)

    const uint16_t* __restrict__ xrow[G];
#pragma unroll
    for (int g = 0; g < G; ++g) {
        const int c   = (g < cnt) ? gc[gid * G + g] : 0;
        const int tok = xids[c * R + rw];
        xrow[g] = xb + (size_t)tok * K + s * KS + jq * 16;
    }

    float4 acc[G];
#pragma unroll
    for (int g = 0; g < G; ++g) acc[g] = make_float4(0.f, 0.f, 0.f, 0.f);

    const int wsw = wave << 4;                  // read swizzle (jq = p>>3 = wave)
    const int p1  = wave * 8 + kq;              // first pair index this lane reads
    const int rr  = (4 * r4) ^ wsw;

    for (int tile = 0; tile < NTILES; ++tile) {
        // ---- stage: straight uint4 copy of packed bf16 (no unpack) ----
#pragma unroll
        for (int g = 0; g < G; ++g) {
            if (g < cnt) {
                const uint4* src = (const uint4*)(xrow[g] + tile * TK);
                uint4 u0 = src[0], u1 = src[1];
                uint32_t* dst = &xs[g * 2048 + (jq * 8) * R + rsw];
                dst[0 * R] = u0.x; dst[1 * R] = u0.y; dst[2 * R] = u0.z; dst[3 * R] = u0.w;
                dst[4 * R] = u1.x; dst[5 * R] = u1.y; dst[6 * R] = u1.z; dst[7 * R] = u1.w;
            }
        }
        __syncthreads();

        // ---- A fragment: loaded ONCE, reused across all g (the 4x win) ----
        const int k0 = s * KS + tile * TK + wave * 16 + 2 * kq;
        const float* __restrict__ Ap = Aw + (size_t)k0 * R + 4 * r4;
        const float4 a0 = *(const float4*)(Ap);            // k0
        const float4 a1 = *(const float4*)(Ap + R);        // k0+1
        const float4 a2 = *(const float4*)(Ap + 8 * R);    // k0+8
        const float4 a3 = *(const float4*)(Ap + 9 * R);    // k0+9

#pragma unroll
        for (int g = 0; g < G; ++g) {
            if (g < cnt) {
                const uint32_t* b = &xs[g * 2048];
                const uint4 f1 = *(const uint4*)&b[p1 * R + rr];        // k0,k0+1
                const uint4 f2 = *(const uint4*)&b[(p1 + 4) * R + rr];  // k0+8,k0+9
                acc[g].x = fmaf(bflo(f1.x), a0.x, acc[g].x);
                acc[g].y = fmaf(bflo(f1.y), a0.y, acc[g].y);
                acc[g].z = fmaf(bflo(f1.z), a0.z, acc[g].z);
                acc[g].w = fmaf(bflo(f1.w), a0.w, acc[g].w);
                acc[g].x = fmaf(bfhi(f1.x), a1.x, acc[g].x);
                acc[g].y = fmaf(bfhi(f1.y), a1.y, acc[g].y);
                acc[g].z = fmaf(bfhi(f1.z), a1.z, acc[g].z);
                acc[g].w = fmaf(bfhi(f1.w), a1.w, acc[g].w);
                acc[g].x = fmaf(bflo(f2.x), a2.x, acc[g].x);
                acc[g].y = fmaf(bflo(f2.y), a2.y, acc[g].y);
                acc[g].z = fmaf(bflo(f2.z), a2.z, acc[g].z);
                acc[g].w = fmaf(bflo(f2.w), a2.w, acc[g].w);
                acc[g].x = fmaf(bfhi(f2.x), a3.x, acc[g].x);
                acc[g].y = fmaf(bfhi(f2.y), a3.y, acc[g].y);
                acc[g].z = fmaf(bfhi(f2.z), a3.z, acc[g].z);
                acc[g].w = fmaf(bfhi(f2.w), a3.w, acc[g].w);
            }
        }
        __syncthreads();
    }

    // ---- reduce over kq lanes, then waves; one atomic per output element ----
#pragma unroll
    for (int g = 0; g < G; ++g) {
#pragma unroll
        for (int m = 16; m < 64; m <<= 1) {
            acc[g].x += __shfl_xor(acc[g].x, m, 64);
            acc[g].y += __shfl_xor(acc[g].y, m, 64);
            acc[g].z += __shfl_xor(acc[g].z, m, 64);
            acc[g].w += __shfl_xor(acc[g].w, m, 64);
        }
    }
    if (kq == 0) {
#pragma unroll
        for (int g = 0; g < G; ++g)
            *(float4*)&red[(g * NW + wave) * R + 4 * r4] = acc[g];
    }
    __syncthreads();
    {
        const int g = wave;          // wave g writes combo g of the group
        if (g < cnt) {
            const int c = gc[gid * G + g];
            const float sum = red[(g * NW + 0) * R + lane] + red[(g * NW + 1) * R + lane]
                            + red[(g * NW + 2) * R + lane] + red[(g * NW + 3) * R + lane];
            atomicAdd(&out[c * R + lane], sum);
        }
    }
}

// ---- fallback (ws too small): R2-style fp32 kernel, ungrouped ----
__global__ __launch_bounds__(NT)
void lora_fallback(const float* __restrict__ x,
                   const int*   __restrict__ xids,
                   const int*   __restrict__ wids,
                   const float* __restrict__ A,
                   float*       __restrict__ out)
{
    __shared__ float xsf[TK * R];
    __shared__ float red[NW * R];
    const int bid  = blockIdx.x;
    const int c    = bid >> 3;
    const int s    = bid & 7;
    const int t    = threadIdx.x;
    const int wave = t >> 6;
    const int lane = t & 63;
    const int r4   = lane & 15;
    const int kq   = lane >> 4;
    const int wid  = wids[c];
    const float* __restrict__ Aw = A + (size_t)wid * (K * R);
    const int rw  = t >> 2;
    const int jq  = t & 3;
    const int tok = xids[c * R + rw];
    const float* __restrict__ xrow = x + (size_t)tok * K + s * KS + jq * 16;
    float4 acc = make_float4(0.f, 0.f, 0.f, 0.f);
    for (int tile = 0; tile < NTILES; ++tile) {
        const float4* src = (const float4*)(xrow + tile * TK);
#pragma unroll
        for (int ii = 0; ii < 4; ++ii) {
            float4 v = src[ii];
            const int kk = jq * 16 + ii * 4;
            xsf[(kk + 0) * R + rw] = v.x;
            xsf[(kk + 1) * R + rw] = v.y;
            xsf[(kk + 2) * R + rw] = v.z;
            xsf[(kk + 3) * R + rw] = v.w;
        }
        __syncthreads();
        const int kw = wave * 16 + kq;
        const float* __restrict__ Ap =
            Aw + (size_t)(s * KS + tile * TK + kw) * R + 4 * r4;
#pragma unroll
        for (int i = 0; i < 4; ++i) {
            float4 av = *(const float4*)(Ap + (size_t)(4 * i) * R);
            float4 xv = *(const float4*)(&xsf[(kw + 4 * i) * R + 4 * r4]);
            acc.x = fmaf(xv.x, av.x, acc.x);
            acc.y = fmaf(xv.y, av.y, acc.y);
            acc.z = fmaf(xv.z, av.z, acc.z);
            acc.w = fmaf(xv.w, av.w, acc.w);
        }
        __syncthreads();
    }
#pragma unroll
    for (int m = 16; m < 64; m <<= 1) {
        acc.x += __shfl_xor(acc.x, m, 64);
        acc.y += __shfl_xor(acc.y, m, 64);
        acc.z += __shfl_xor(acc.z, m, 64);
        acc.w += __shfl_xor(acc.w, m, 64);
    }
    if (kq == 0) {
        float* rd = &red[wave * R + 4 * r4];
        rd[0] = acc.x; rd[1] = acc.y; rd[2] = acc.z; rd[3] = acc.w;
    }
    __syncthreads();
    if (wave == 0) {
        float sum = red[lane] + red[R + lane] + red[2 * R + lane] + red[3 * R + lane];
        atomicAdd(&out[c * R + lane], sum);
    }
}

extern "C" void kernel_launch(void* const* d_in, const int* in_sizes, int n_in,
                              void* d_out, int out_size, void* d_ws, size_t ws_size,
                              hipStream_t stream)
{
    (void)in_sizes; (void)n_in;
    const float* x    = (const float*)d_in[0];
    const int*   xids = (const int*)d_in[1];
    const int*   wids = (const int*)d_in[2];
    const float* A    = (const float*)d_in[3];
    float* out        = (float*)d_out;

    hipMemsetAsync(out, 0, (size_t)out_size * sizeof(float), stream);

    if (ws_size >= WS_NEEDED) {
        int*      wsi  = (int*)d_ws;
        int*      gcnt = wsi;
        int*      gwid = wsi + 256;
        int*      gc   = wsi + 512;
        uint16_t* xb   = (uint16_t*)((char*)d_ws + WS_XB_OFF);
        hipLaunchKernelGGL(groups_build, dim3(1), dim3(CBS), 0, stream,
                           wids, gcnt, gwid, gc);
        hipLaunchKernelGGL(cvt_x, dim3(BATCH * K / 4 / 256), dim3(256), 0, stream, x, xb);
        hipLaunchKernelGGL(lora_main, dim3(MAXG * SPLIT), dim3(NT), 0, stream,
                           xids, A, xb, gcnt, gwid, gc, out);
    } else {
        hipLaunchKernelGGL(lora_fallback, dim3(CBS * SPLIT), dim3(NT), 0, stream,
                           x, xids, wids, A, out);
    }
}